// Round 5
// baseline (82.821 us; speedup 1.0000x reference)
//
#include <hip/hip_runtime.h>
#include <hip/hip_bf16.h>

#define NB 8
#define NS 2048
#define ND 1024
#define NE 8

typedef unsigned short ushort_t;
typedef __attribute__((ext_vector_type(8))) short bf16x8;
typedef __attribute__((ext_vector_type(4))) float f32x4;

__device__ __forceinline__ unsigned short f2bf(float f) {
    union { float f; unsigned int u; } x; x.f = f;
    unsigned int u = x.u + 0x7fffu + ((x.u >> 16) & 1u);
    return (unsigned short)(u >> 16);
}

// packed 2x f32 -> 2x bf16 (RNE); compiler emits v_cvt_pk_bf16_f32
__device__ __forceinline__ unsigned pk2(float a, float b) {
    __hip_bfloat162 h = __float22bfloat162_rn(make_float2(a, b));
    union { __hip_bfloat162 h; unsigned u; } c; c.h = h; return c.u;
}

__device__ __forceinline__ void gload16(const void* g, void* l) {
    __builtin_amdgcn_global_load_lds(
        (const __attribute__((address_space(1))) unsigned int*)g,
        (__attribute__((address_space(3))) unsigned int*)l, 16, 0, 0);
}

// ---------------- routing: top-k gate coefs + expert counts ----------------
__global__ void routing_kernel(const float* __restrict__ scores,
                               const int* __restrict__ kp,
                               float* __restrict__ coef,
                               float* __restrict__ counts) {
    __shared__ int selS[NB][NE];
    int t = threadIdx.x;
    int k = *kp;
    if (t < NB) {
        float s[NE];
#pragma unroll
        for (int e = 0; e < NE; ++e) s[e] = scores[t * NE + e];
        bool sel[NE];
#pragma unroll
        for (int e = 0; e < NE; ++e) sel[e] = false;
        float sum = 0.f;
        for (int j = 0; j < k; ++j) {
            int best = 0; float bv = -3.4e38f;
#pragma unroll
            for (int e = 0; e < NE; ++e)
                if (!sel[e] && s[e] > bv) { bv = s[e]; best = e; }
            sel[best] = true; sum += bv;
        }
        float scale = 1.f / (sum + 1e-8f);
#pragma unroll
        for (int e = 0; e < NE; ++e) {
            coef[t * NE + e] = sel[e] ? scale * s[e] : 0.f;
            selS[t][e] = sel[e] ? 1 : 0;
        }
    }
    __syncthreads();
    if (t < NE) {
        int c = 0;
#pragma unroll
        for (int b = 0; b < NB; ++b) c += selS[b][t];
        counts[t] = (float)c;
    }
}

// ---------------- combined bias ----------------
__global__ void bias_kernel(const float* __restrict__ eb,
                            const float* __restrict__ coef,
                            float* __restrict__ bias) {
    int b = blockIdx.y;
    int f = blockIdx.x * 256 + threadIdx.x;
    float acc = 0.f;
#pragma unroll
    for (int e = 0; e < NE; ++e) {
        float c = coef[b * NE + e];
        if (c != 0.f) acc += c * eb[e * ND + f];
    }
    bias[b * ND + f] = acc;
}

// ---- combined weights, TRANSPOSED to [b][f][d] bf16 ----
__global__ void combine_kernel(const float* __restrict__ W,
                               const float* __restrict__ coef,
                               ushort_t* __restrict__ wct) {
    __shared__ float tile[64][65];
    int b = blockIdx.z;
    int d0 = blockIdx.y * 64, f0 = blockIdx.x * 64;
    int t = threadIdx.x;
    int lr = t >> 4;
    int lc = (t & 15) * 4;
    float4 acc[4];
#pragma unroll
    for (int it = 0; it < 4; ++it) acc[it] = make_float4(0.f, 0.f, 0.f, 0.f);
#pragma unroll
    for (int e = 0; e < NE; ++e) {
        float c = coef[b * NE + e];
        if (c != 0.f) {
            const float* We = W + ((size_t)e * ND * ND);
#pragma unroll
            for (int it = 0; it < 4; ++it) {
                int d = d0 + lr + it * 16;
                float4 v = *(const float4*)(We + (size_t)d * ND + f0 + lc);
                acc[it].x += c * v.x; acc[it].y += c * v.y;
                acc[it].z += c * v.z; acc[it].w += c * v.w;
            }
        }
    }
#pragma unroll
    for (int it = 0; it < 4; ++it) {
        int r = lr + it * 16;
        tile[r][lc + 0] = acc[it].x; tile[r][lc + 1] = acc[it].y;
        tile[r][lc + 2] = acc[it].z; tile[r][lc + 3] = acc[it].w;
    }
    __syncthreads();
    int dl = t & 63;
    int frow = t >> 6;
    ushort_t* dst = wct + (size_t)b * ND * ND + (size_t)f0 * ND + d0 + dl;
#pragma unroll
    for (int it = 0; it < 16; ++it) {
        int f = frow + it * 4;
        dst[(size_t)f * ND] = f2bf(tile[dl][f]);
    }
}

// ====== 256x256 8-wave GEMM, BK=64, fused fp32->bf16 A-staging ======
// out[b] = x[b] @ WcT[b]^T + bias[b]; x fp32, WcT bf16
__global__ __launch_bounds__(512, 2) void gemm_kernel(const float* __restrict__ x,
                                                      const ushort_t* __restrict__ wct,
                                                      const float* __restrict__ bias,
                                                      float* __restrict__ out) {
    __shared__ ushort_t ldsA[2][256 * 64];   // 2 x 32 KiB
    __shared__ ushort_t ldsB[2][256 * 64];   // 2 x 32 KiB

    int bid = blockIdx.x;
    int b = bid & 7;                 // batch -> XCD (round-robin % 8)
    int tile = bid >> 3;
    int m0 = (tile >> 2) * 256;
    int n0 = (tile & 3) * 256;
    const float*    A  = x   + ((size_t)b * NS * ND) + (size_t)m0 * ND;
    const ushort_t* Bt = wct + ((size_t)b * ND * ND) + (size_t)n0 * ND;

    int t = threadIdx.x, lane = t & 63, wave = t >> 6;
    int wm = wave >> 2, wn = wave & 3;          // 2 x 4 wave grid
    int fr = lane & 15, fq = lane >> 4;

    // ---- A reg-staging map: thread t -> row t>>1 (0..255), half h = t&1 ----
    int arow = t >> 1, ah = t & 1;
    const float* xA = A + (size_t)arow * ND;    // + kt*64 + (ah*4+j)*8
    ushort_t* wA[2];
#pragma unroll
    for (int bb = 0; bb < 2; ++bb) wA[bb] = &ldsA[bb][0] + arow * 64;   // +swizzled slot*8

    // ---- B staging source (pre-swizzled slot8 ^= row&7; LDS dest linear) ----
    int srow = lane >> 3;                       // 0..7
    int sslot = (lane & 7) ^ srow;
    const ushort_t* gB[4];
#pragma unroll
    for (int i = 0; i < 4; ++i) {
        int r = (i * 8 + wave) * 8 + srow;      // 0..255
        gB[i] = Bt + (size_t)r * ND + sslot * 8;
    }

    // ---- per-lane LDS fragment byte offsets (k0); k1 -> ^64 ----
    int slotr = (fq ^ (fr & 7)) * 16;
    int aoff[8], boff[4];
#pragma unroll
    for (int mi = 0; mi < 8; ++mi) aoff[mi] = (wm * 128 + mi * 16 + fr) * 128 + slotr;
#pragma unroll
    for (int nj = 0; nj < 4; ++nj) boff[nj] = (wn * 64 + nj * 16 + fr) * 128 + slotr;

    f32x4 acc[8][4];
#pragma unroll
    for (int i = 0; i < 8; ++i)
#pragma unroll
        for (int j = 0; j < 4; ++j) acc[i][j] = (f32x4){0.f, 0.f, 0.f, 0.f};

    const int NT = ND / 64;   // 16 K-tiles

    // ---- prologue: stage K-tile 0 into buf 0 ----
    {
        float4 pa[8];
#pragma unroll
        for (int j = 0; j < 4; ++j) {
            pa[j * 2]     = *(const float4*)(xA + (ah * 4 + j) * 8);
            pa[j * 2 + 1] = *(const float4*)(xA + (ah * 4 + j) * 8 + 4);
        }
#pragma unroll
        for (int i = 0; i < 4; ++i)
            gload16(gB[i], (char*)&ldsB[0][0] + (i * 8 + wave) * 1024);
#pragma unroll
        for (int j = 0; j < 4; ++j) {
            uint4 o;
            o.x = pk2(pa[j * 2].x, pa[j * 2].y);
            o.y = pk2(pa[j * 2].z, pa[j * 2].w);
            o.z = pk2(pa[j * 2 + 1].x, pa[j * 2 + 1].y);
            o.w = pk2(pa[j * 2 + 1].z, pa[j * 2 + 1].w);
            *(uint4*)(wA[0] + ((ah * 4 + j) ^ (arow & 7)) * 8) = o;
        }
        asm volatile("s_waitcnt vmcnt(0) lgkmcnt(0)" ::: "memory");
        __builtin_amdgcn_s_barrier();
    }

    for (int kt = 0; kt < NT; ++kt) {
        const char* lA = (const char*)&ldsA[kt & 1][0];
        const char* lB = (const char*)&ldsB[kt & 1][0];
        bool pre = (kt + 1 < NT);
        int nb = (kt + 1) & 1;
        char* dB = (char*)&ldsB[nb][0];

        __builtin_amdgcn_sched_barrier(0);
        bf16x8 bf0[4], bf1[4], a0[4], a1[4], a2[4], a3[4];
        // issue: B k0(4), A g0(4), B k1(4), A g1(4)  -> 16 outstanding ds
#pragma unroll
        for (int nj = 0; nj < 4; ++nj) bf0[nj] = *(const bf16x8*)(lB + boff[nj]);
#pragma unroll
        for (int mi = 0; mi < 4; ++mi) a0[mi] = *(const bf16x8*)(lA + aoff[mi]);
#pragma unroll
        for (int nj = 0; nj < 4; ++nj) bf1[nj] = *(const bf16x8*)(lB + (boff[nj] ^ 64));
#pragma unroll
        for (int mi = 0; mi < 4; ++mi) a1[mi] = *(const bf16x8*)(lA + aoff[mi + 4]);
        // A(kt+1): 8 fp32 dwordx4 -> regs (latency hidden under this tile)
        float4 pa[8];
        if (pre) {
            const float* xk = xA + (kt + 1) * 64;
#pragma unroll
            for (int j = 0; j < 4; ++j) {
                pa[j * 2]     = *(const float4*)(xk + (ah * 4 + j) * 8);
                pa[j * 2 + 1] = *(const float4*)(xk + (ah * 4 + j) * 8 + 4);
            }
        }
        __builtin_amdgcn_sched_barrier(0);
        asm volatile("s_waitcnt lgkmcnt(8)" ::: "memory");   // Bk0 + Ag0 landed
        __builtin_amdgcn_sched_barrier(0);
        __builtin_amdgcn_s_setprio(1);
#pragma unroll
        for (int mi = 0; mi < 4; ++mi)
#pragma unroll
            for (int nj = 0; nj < 4; ++nj)
                acc[mi][nj] = __builtin_amdgcn_mfma_f32_16x16x32_bf16(a0[mi], bf0[nj], acc[mi][nj], 0, 0, 0);
        __builtin_amdgcn_s_setprio(0);
        // issue A g2 (k1, m0-3); stage B(kt+1)
#pragma unroll
        for (int mi = 0; mi < 4; ++mi) a2[mi] = *(const bf16x8*)(lA + (aoff[mi] ^ 64));
        if (pre) {
#pragma unroll
            for (int i = 0; i < 4; ++i) {
                gB[i] += 64;
                gload16(gB[i], dB + (i * 8 + wave) * 1024);
            }
        }
        __builtin_amdgcn_sched_barrier(0);
        asm volatile("s_waitcnt lgkmcnt(4)" ::: "memory");   // Bk1 + Ag1 landed
        __builtin_amdgcn_sched_barrier(0);
        __builtin_amdgcn_s_setprio(1);
#pragma unroll
        for (int mi = 0; mi < 4; ++mi)
#pragma unroll
            for (int nj = 0; nj < 4; ++nj)
                acc[mi + 4][nj] = __builtin_amdgcn_mfma_f32_16x16x32_bf16(a1[mi], bf0[nj], acc[mi + 4][nj], 0, 0, 0);
        __builtin_amdgcn_s_setprio(0);
        // issue A g3 (k1, m4-7)
#pragma unroll
        for (int mi = 0; mi < 4; ++mi) a3[mi] = *(const bf16x8*)(lA + (aoff[mi + 4] ^ 64));
        __builtin_amdgcn_sched_barrier(0);
        asm volatile("s_waitcnt lgkmcnt(4)" ::: "memory");   // Ag2 landed
        __builtin_amdgcn_sched_barrier(0);
        __builtin_amdgcn_s_setprio(1);
#pragma unroll
        for (int mi = 0; mi < 4; ++mi)
#pragma unroll
            for (int nj = 0; nj < 4; ++nj)
                acc[mi][nj] = __builtin_amdgcn_mfma_f32_16x16x32_bf16(a2[mi], bf1[nj], acc[mi][nj], 0, 0, 0);
        __builtin_amdgcn_s_setprio(0);
        __builtin_amdgcn_sched_barrier(0);
        asm volatile("s_waitcnt lgkmcnt(0)" ::: "memory");   // Ag3 landed
        __builtin_amdgcn_sched_barrier(0);
        __builtin_amdgcn_s_setprio(1);
#pragma unroll
        for (int mi = 0; mi < 4; ++mi)
#pragma unroll
            for (int nj = 0; nj < 4; ++nj)
                acc[mi + 4][nj] = __builtin_amdgcn_mfma_f32_16x16x32_bf16(a3[mi], bf1[nj], acc[mi + 4][nj], 0, 0, 0);
        __builtin_amdgcn_s_setprio(0);
        __builtin_amdgcn_sched_barrier(0);
        if (pre) {
            // A fp32 regs landed (8 loads issued first; 4 B glds after)
            asm volatile("s_waitcnt vmcnt(4)" ::: "memory");
            __builtin_amdgcn_sched_barrier(0);
#pragma unroll
            for (int j = 0; j < 4; ++j) {
                uint4 o;
                o.x = pk2(pa[j * 2].x, pa[j * 2].y);
                o.y = pk2(pa[j * 2].z, pa[j * 2].w);
                o.z = pk2(pa[j * 2 + 1].x, pa[j * 2 + 1].y);
                o.w = pk2(pa[j * 2 + 1].z, pa[j * 2 + 1].w);
                *(uint4*)(wA[nb] + ((ah * 4 + j) ^ (arow & 7)) * 8) = o;
            }
            __builtin_amdgcn_sched_barrier(0);
            asm volatile("s_waitcnt vmcnt(0) lgkmcnt(0)" ::: "memory");  // B staged + A writes done
            __builtin_amdgcn_s_barrier();
        }
    }

    // ---- epilogue: bias + fp32 store ----
    const float* bs = bias + b * ND;
    float* O = out + ((size_t)b * NS * ND);
#pragma unroll
    for (int mi = 0; mi < 8; ++mi) {
        int row = m0 + wm * 128 + mi * 16 + fq * 4;
#pragma unroll
        for (int nj = 0; nj < 4; ++nj) {
            int col = n0 + wn * 64 + nj * 16 + fr;
            float bv = bs[col];
            f32x4 v = acc[mi][nj];
#pragma unroll
            for (int r = 0; r < 4; ++r)
                O[(size_t)(row + r) * ND + col] = v[r] + bv;
        }
    }
}

extern "C" void kernel_launch(void* const* d_in, const int* in_sizes, int n_in,
                              void* d_out, int out_size, void* d_ws, size_t ws_size,
                              hipStream_t stream) {
    const float* x      = (const float*)d_in[0];
    const float* scores = (const float*)d_in[1];
    const float* Wx     = (const float*)d_in[2];
    const float* eb     = (const float*)d_in[3];
    const int*   kp     = (const int*)d_in[4];
    float* out = (float*)d_out;
    char* ws = (char*)d_ws;

    float*    coef  = (float*)(ws);
    float*    bias  = (float*)(ws + 1024);
    ushort_t* wct   = (ushort_t*)(ws + 65536);
    float*    counts = out + (size_t)NB * NS * ND;

    routing_kernel<<<1, 64, 0, stream>>>(scores, kp, coef, counts);
    bias_kernel<<<dim3(ND / 256, NB), 256, 0, stream>>>(eb, coef, bias);
    combine_kernel<<<dim3(ND / 64, ND / 64, NB), 256, 0, stream>>>(Wx, coef, wct);
    gemm_kernel<<<256, 512, 0, stream>>>(x, wct, bias, out);
}

// Round 6
// 75.404 us; speedup vs baseline: 1.0984x; 1.0984x over previous
//
#include <hip/hip_runtime.h>

#define NB 8
#define NS 2048
#define ND 1024
#define NE 8

typedef unsigned short ushort_t;
typedef __attribute__((ext_vector_type(8))) short bf16x8;
typedef __attribute__((ext_vector_type(4))) float f32x4;

__device__ __forceinline__ unsigned short f2bf(float f) {
    union { float f; unsigned int u; } x; x.f = f;
    unsigned int u = x.u + 0x7fffu + ((x.u >> 16) & 1u);
    return (unsigned short)(u >> 16);
}

__device__ __forceinline__ void gload16(const void* g, void* l) {
    __builtin_amdgcn_global_load_lds(
        (const __attribute__((address_space(1))) unsigned int*)g,
        (__attribute__((address_space(3))) unsigned int*)l, 16, 0, 0);
}

// ---------------- routing: top-k gate coefs + expert counts ----------------
__global__ void routing_kernel(const float* __restrict__ scores,
                               const int* __restrict__ kp,
                               float* __restrict__ coef,
                               float* __restrict__ counts) {
    __shared__ int selS[NB][NE];
    int t = threadIdx.x;
    int k = *kp;
    if (t < NB) {
        float s[NE];
#pragma unroll
        for (int e = 0; e < NE; ++e) s[e] = scores[t * NE + e];
        bool sel[NE];
#pragma unroll
        for (int e = 0; e < NE; ++e) sel[e] = false;
        float sum = 0.f;
        for (int j = 0; j < k; ++j) {
            int best = 0; float bv = -3.4e38f;
#pragma unroll
            for (int e = 0; e < NE; ++e)
                if (!sel[e] && s[e] > bv) { bv = s[e]; best = e; }
            sel[best] = true; sum += bv;
        }
        float scale = 1.f / (sum + 1e-8f);
#pragma unroll
        for (int e = 0; e < NE; ++e) {
            coef[t * NE + e] = sel[e] ? scale * s[e] : 0.f;
            selS[t][e] = sel[e] ? 1 : 0;
        }
    }
    __syncthreads();
    if (t < NE) {
        int c = 0;
#pragma unroll
        for (int b = 0; b < NB; ++b) c += selS[b][t];
        counts[t] = (float)c;
    }
}

// ---------------- combined bias ----------------
__global__ void bias_kernel(const float* __restrict__ eb,
                            const float* __restrict__ coef,
                            float* __restrict__ bias) {
    int b = blockIdx.y;
    int f = blockIdx.x * 256 + threadIdx.x;
    float acc = 0.f;
#pragma unroll
    for (int e = 0; e < NE; ++e) {
        float c = coef[b * NE + e];
        if (c != 0.f) acc += c * eb[e * ND + f];
    }
    bias[b * ND + f] = acc;
}

// ---- combined weights, TRANSPOSED to [b][f][d] bf16 ----
__global__ void combine_kernel(const float* __restrict__ W,
                               const float* __restrict__ coef,
                               ushort_t* __restrict__ wct) {
    __shared__ float tile[64][65];
    int b = blockIdx.z;
    int d0 = blockIdx.y * 64, f0 = blockIdx.x * 64;
    int t = threadIdx.x;
    int lr = t >> 4;
    int lc = (t & 15) * 4;
    float4 acc[4];
#pragma unroll
    for (int it = 0; it < 4; ++it) acc[it] = make_float4(0.f, 0.f, 0.f, 0.f);
#pragma unroll
    for (int e = 0; e < NE; ++e) {
        float c = coef[b * NE + e];
        if (c != 0.f) {
            const float* We = W + ((size_t)e * ND * ND);
#pragma unroll
            for (int it = 0; it < 4; ++it) {
                int d = d0 + lr + it * 16;
                float4 v = *(const float4*)(We + (size_t)d * ND + f0 + lc);
                acc[it].x += c * v.x; acc[it].y += c * v.y;
                acc[it].z += c * v.z; acc[it].w += c * v.w;
            }
        }
    }
#pragma unroll
    for (int it = 0; it < 4; ++it) {
        int r = lr + it * 16;
        tile[r][lc + 0] = acc[it].x; tile[r][lc + 1] = acc[it].y;
        tile[r][lc + 2] = acc[it].z; tile[r][lc + 3] = acc[it].w;
    }
    __syncthreads();
    int dl = t & 63;
    int frow = t >> 6;
    ushort_t* dst = wct + (size_t)b * ND * ND + (size_t)f0 * ND + d0 + dl;
#pragma unroll
    for (int it = 0; it < 16; ++it) {
        int f = frow + it * 4;
        dst[(size_t)f * ND] = f2bf(tile[dl][f]);
    }
}

// ---------------- x fp32 -> bf16 ----------------
__global__ void convert_kernel(const float* __restrict__ x, ushort_t* __restrict__ xb) {
    int i = blockIdx.x * 256 + threadIdx.x;
    const float4* p = (const float4*)x + 2 * (size_t)i;
    float4 a = p[0], b = p[1];
    uint4 o;
    o.x = (unsigned)f2bf(a.x) | ((unsigned)f2bf(a.y) << 16);
    o.y = (unsigned)f2bf(a.z) | ((unsigned)f2bf(a.w) << 16);
    o.z = (unsigned)f2bf(b.x) | ((unsigned)f2bf(b.y) << 16);
    o.w = (unsigned)f2bf(b.z) | ((unsigned)f2bf(b.w) << 16);
    ((uint4*)xb)[i] = o;
}

// ====== 256x128 8-wave GEMM, BK=64, 3-buffer LDS, counted vmcnt(6) ======
// Loads for tile t+2 stay in flight across tile t's barrier (no drain-0).
__global__ __launch_bounds__(512, 2) void gemm_kernel(const ushort_t* __restrict__ xb,
                                                      const ushort_t* __restrict__ wct,
                                                      const float* __restrict__ bias,
                                                      float* __restrict__ out) {
    __shared__ ushort_t ldsA[3][256 * 64];   // 3 x 32 KiB
    __shared__ ushort_t ldsB[3][128 * 64];   // 3 x 16 KiB

    int bid = blockIdx.x;
    int b = bid & 7;                 // batch -> XCD (round-robin % 8)
    int tile = bid >> 3;             // 0..63
    int m0 = (tile >> 3) * 256;      // 8 M-tiles
    int n0 = (tile & 7) * 128;       // 8 N-tiles
    const ushort_t* A  = xb  + ((size_t)b * NS * ND) + (size_t)m0 * ND;
    const ushort_t* Bt = wct + ((size_t)b * ND * ND) + (size_t)n0 * ND;

    int t = threadIdx.x, lane = t & 63, wave = t >> 6;
    int wm = wave >> 1, wn = wave & 1;          // 4 x 2 wave grid
    int fr = lane & 15, fq = lane >> 4;

    // ---- staging source (pre-swizzled slot8 ^= row&7; LDS dest linear) ----
    int srow = lane >> 3;                       // 0..7
    int sslot = (lane & 7) ^ srow;
    const ushort_t* gA[4];
    const ushort_t* gB[2];
#pragma unroll
    for (int i = 0; i < 4; ++i)
        gA[i] = A  + (size_t)(wave * 32 + i * 8 + srow) * ND + sslot * 8;
#pragma unroll
    for (int i = 0; i < 2; ++i)
        gB[i] = Bt + (size_t)(wave * 16 + i * 8 + srow) * ND + sslot * 8;

    // ---- per-lane LDS fragment byte offsets (k0); k1 -> ^64 ----
    int slotr = (fq ^ (fr & 7)) * 16;
    int aoff[4], boff[4];
#pragma unroll
    for (int mi = 0; mi < 4; ++mi) aoff[mi] = (wm * 64 + mi * 16 + fr) * 128 + slotr;
#pragma unroll
    for (int nj = 0; nj < 4; ++nj) boff[nj] = (wn * 64 + nj * 16 + fr) * 128 + slotr;

    f32x4 acc[4][4];
#pragma unroll
    for (int i = 0; i < 4; ++i)
#pragma unroll
        for (int j = 0; j < 4; ++j) acc[i][j] = (f32x4){0.f, 0.f, 0.f, 0.f};

    const int NT = ND / 64;   // 16 K-tiles

    // ---- prologue: stage tiles 0,1 into bufs 0,1 (6 gloads each) ----
#pragma unroll
    for (int T = 0; T < 2; ++T) {
#pragma unroll
        for (int i = 0; i < 4; ++i)
            gload16(gA[i] + T * 64, &ldsA[T][(wave * 32 + i * 8) * 64]);
#pragma unroll
        for (int i = 0; i < 2; ++i)
            gload16(gB[i] + T * 64, &ldsB[T][(wave * 16 + i * 8) * 64]);
    }
    asm volatile("s_waitcnt vmcnt(6)" ::: "memory");   // tile 0 landed
    __builtin_amdgcn_s_barrier();

    int cur = 0;
    for (int kt = 0; kt < NT; ++kt) {
        const char* lA = (const char*)&ldsA[cur][0];
        const char* lB = (const char*)&ldsB[cur][0];
        int sq = cur + 2; if (sq >= 3) sq -= 3;    // buffer for tile kt+2

        __builtin_amdgcn_sched_barrier(0);
        bf16x8 b0[4], a0[4], b1[4], a1[4];
        // issue all 16 ds_reads: Bk0, Ak0, Bk1, Ak1
#pragma unroll
        for (int nj = 0; nj < 4; ++nj) b0[nj] = *(const bf16x8*)(lB + boff[nj]);
#pragma unroll
        for (int mi = 0; mi < 4; ++mi) a0[mi] = *(const bf16x8*)(lA + aoff[mi]);
#pragma unroll
        for (int nj = 0; nj < 4; ++nj) b1[nj] = *(const bf16x8*)(lB + (boff[nj] ^ 64));
#pragma unroll
        for (int mi = 0; mi < 4; ++mi) a1[mi] = *(const bf16x8*)(lA + (aoff[mi] ^ 64));
        // stage tile kt+2 into buf sq (6 gloads, stay in flight past barrier)
        if (kt + 2 < NT) {
            int ko = (kt + 2) * 64;
#pragma unroll
            for (int i = 0; i < 4; ++i)
                gload16(gA[i] + ko, &ldsA[sq][(wave * 32 + i * 8) * 64]);
#pragma unroll
            for (int i = 0; i < 2; ++i)
                gload16(gB[i] + ko, &ldsB[sq][(wave * 16 + i * 8) * 64]);
        }
        __builtin_amdgcn_sched_barrier(0);
        asm volatile("s_waitcnt lgkmcnt(8)" ::: "memory");   // Bk0 + Ak0 landed
        __builtin_amdgcn_sched_barrier(0);
        __builtin_amdgcn_s_setprio(1);
#pragma unroll
        for (int mi = 0; mi < 4; ++mi)
#pragma unroll
            for (int nj = 0; nj < 4; ++nj)
                acc[mi][nj] = __builtin_amdgcn_mfma_f32_16x16x32_bf16(a0[mi], b0[nj], acc[mi][nj], 0, 0, 0);
        __builtin_amdgcn_s_setprio(0);
        __builtin_amdgcn_sched_barrier(0);
        asm volatile("s_waitcnt lgkmcnt(0)" ::: "memory");   // Bk1 + Ak1 landed
        __builtin_amdgcn_sched_barrier(0);
        __builtin_amdgcn_s_setprio(1);
#pragma unroll
        for (int mi = 0; mi < 4; ++mi)
#pragma unroll
            for (int nj = 0; nj < 4; ++nj)
                acc[mi][nj] = __builtin_amdgcn_mfma_f32_16x16x32_bf16(a1[mi], b1[nj], acc[mi][nj], 0, 0, 0);
        __builtin_amdgcn_s_setprio(0);
        __builtin_amdgcn_sched_barrier(0);
        // counted end-of-tile wait: tile kt+1's 6 loads retired; kt+2's stay in flight
        if (kt + 2 < NT) {
            asm volatile("s_waitcnt vmcnt(6)" ::: "memory");
        } else if (kt + 2 == NT) {
            asm volatile("s_waitcnt vmcnt(0)" ::: "memory");
        }
        if (kt + 1 < NT) __builtin_amdgcn_s_barrier();
        cur += 1; if (cur == 3) cur = 0;
    }

    // ---- epilogue: bias + fp32 store ----
    const float* bs = bias + b * ND;
    float* O = out + ((size_t)b * NS * ND);
#pragma unroll
    for (int mi = 0; mi < 4; ++mi) {
        int row = m0 + wm * 64 + mi * 16 + fq * 4;
#pragma unroll
        for (int nj = 0; nj < 4; ++nj) {
            int col = n0 + wn * 64 + nj * 16 + fr;
            float bv = bs[col];
            f32x4 v = acc[mi][nj];
#pragma unroll
            for (int r = 0; r < 4; ++r)
                O[(size_t)(row + r) * ND + col] = v[r] + bv;
        }
    }
}

extern "C" void kernel_launch(void* const* d_in, const int* in_sizes, int n_in,
                              void* d_out, int out_size, void* d_ws, size_t ws_size,
                              hipStream_t stream) {
    const float* x      = (const float*)d_in[0];
    const float* scores = (const float*)d_in[1];
    const float* Wx     = (const float*)d_in[2];
    const float* eb     = (const float*)d_in[3];
    const int*   kp     = (const int*)d_in[4];
    float* out = (float*)d_out;
    char* ws = (char*)d_ws;

    float*    coef  = (float*)(ws);
    float*    bias  = (float*)(ws + 1024);
    ushort_t* xbuf  = (ushort_t*)(ws + 65536);
    ushort_t* wct   = (ushort_t*)(ws + 65536 + (size_t)NB * NS * ND * 2);
    float*    counts = out + (size_t)NB * NS * ND;

    routing_kernel<<<1, 64, 0, stream>>>(scores, kp, coef, counts);
    bias_kernel<<<dim3(ND / 256, NB), 256, 0, stream>>>(eb, coef, bias);
    combine_kernel<<<dim3(ND / 64, ND / 64, NB), 256, 0, stream>>>(Wx, coef, wct);
    convert_kernel<<<dim3(NB * NS * ND / 8 / 256), 256, 0, stream>>>(x, xbuf);
    gemm_kernel<<<512, 512, 0, stream>>>(xbuf, wct, bias, out);
}

// Round 7
// 67.184 us; speedup vs baseline: 1.2328x; 1.1224x over previous
//
#include <hip/hip_runtime.h>

#define NB 8
#define NS 2048
#define ND 1024
#define NE 8

typedef unsigned short ushort_t;
typedef __attribute__((ext_vector_type(8))) short bf16x8;
typedef __attribute__((ext_vector_type(4))) float f32x4;

__device__ __forceinline__ unsigned short f2bf(float f) {
    union { float f; unsigned int u; } x; x.f = f;
    unsigned int u = x.u + 0x7fffu + ((x.u >> 16) & 1u);
    return (unsigned short)(u >> 16);
}

__device__ __forceinline__ void gload16(const void* g, void* l) {
    __builtin_amdgcn_global_load_lds(
        (const __attribute__((address_space(1))) unsigned int*)g,
        (__attribute__((address_space(3))) unsigned int*)l, 16, 0, 0);
}

// local top-k gate coefs for one batch row (deterministic tie-break = first index)
__device__ __forceinline__ void coef_local(const float* __restrict__ scores,
                                           int b, int k, float* cf) {
    float s[NE];
#pragma unroll
    for (int e = 0; e < NE; ++e) s[e] = scores[b * NE + e];
    bool sel[NE];
#pragma unroll
    for (int e = 0; e < NE; ++e) sel[e] = false;
    float sum = 0.f;
    for (int j = 0; j < k; ++j) {
        int best = 0; float bv = -3.4e38f;
#pragma unroll
        for (int e = 0; e < NE; ++e)
            if (!sel[e] && s[e] > bv) { bv = s[e]; best = e; }
        sel[best] = true; sum += bv;
    }
    float scale = 1.f / (sum + 1e-8f);
#pragma unroll
    for (int e = 0; e < NE; ++e) cf[e] = sel[e] ? scale * s[e] : 0.f;
}

// ====== fused prep: combine (2048 blk) | convert (8192 blk) | bias (32) | routing (1) ======
__global__ void prep_kernel(const float* __restrict__ x,
                            const float* __restrict__ scores,
                            const float* __restrict__ W,
                            const float* __restrict__ eb,
                            const int* __restrict__ kp,
                            ushort_t* __restrict__ xb,
                            ushort_t* __restrict__ wct,
                            float* __restrict__ bias,
                            float* __restrict__ counts) {
    __shared__ float tile[64][65];
    __shared__ int selS[NB][NE];
    int bid = blockIdx.x;
    int t = threadIdx.x;

    if (bid < 2048) {
        // ---- combine: wct[b][f][d] = sum_e cf_e * W[e][d][f]  (bf16, transposed) ----
        int b = bid >> 8;
        int f0 = (bid & 15) * 64, d0 = ((bid >> 4) & 15) * 64;
        float cf[NE];
        coef_local(scores, b, kp[0], cf);
        int lr = t >> 4;
        int lc = (t & 15) * 4;
        float4 acc[4];
#pragma unroll
        for (int it = 0; it < 4; ++it) acc[it] = make_float4(0.f, 0.f, 0.f, 0.f);
#pragma unroll
        for (int e = 0; e < NE; ++e) {
            float c = cf[e];
            if (c != 0.f) {
                const float* We = W + ((size_t)e * ND * ND);
#pragma unroll
                for (int it = 0; it < 4; ++it) {
                    int d = d0 + lr + it * 16;
                    float4 v = *(const float4*)(We + (size_t)d * ND + f0 + lc);
                    acc[it].x += c * v.x; acc[it].y += c * v.y;
                    acc[it].z += c * v.z; acc[it].w += c * v.w;
                }
            }
        }
#pragma unroll
        for (int it = 0; it < 4; ++it) {
            int r = lr + it * 16;
            tile[r][lc + 0] = acc[it].x; tile[r][lc + 1] = acc[it].y;
            tile[r][lc + 2] = acc[it].z; tile[r][lc + 3] = acc[it].w;
        }
        __syncthreads();
        int dl = t & 63;
        int frow = t >> 6;
        ushort_t* dst = wct + (size_t)b * ND * ND + (size_t)f0 * ND + d0 + dl;
#pragma unroll
        for (int it = 0; it < 16; ++it) {
            int f = frow + it * 4;
            dst[(size_t)f * ND] = f2bf(tile[dl][f]);
        }
    } else if (bid < 10240) {
        // ---- convert x fp32 -> bf16, 8 elems/thread ----
        size_t i = (size_t)(bid - 2048) * 256 + t;
        const float4* p = (const float4*)x + 2 * i;
        float4 a = p[0], b = p[1];
        uint4 o;
        o.x = (unsigned)f2bf(a.x) | ((unsigned)f2bf(a.y) << 16);
        o.y = (unsigned)f2bf(a.z) | ((unsigned)f2bf(a.w) << 16);
        o.z = (unsigned)f2bf(b.x) | ((unsigned)f2bf(b.y) << 16);
        o.w = (unsigned)f2bf(b.z) | ((unsigned)f2bf(b.w) << 16);
        ((uint4*)xb)[i] = o;
    } else if (bid < 10272) {
        // ---- bias: bc[b][f] = sum_e cf_e * eb[e][f] ----
        int i = bid - 10240;
        int b = i >> 2, f = (i & 3) * 256 + t;
        float cf[NE];
        coef_local(scores, b, kp[0], cf);
        float acc = 0.f;
#pragma unroll
        for (int e = 0; e < NE; ++e)
            if (cf[e] != 0.f) acc += cf[e] * eb[e * ND + f];
        bias[b * ND + f] = acc;
    } else {
        // ---- routing: expert counts (output 1) ----
        int k = kp[0];
        if (t < NB) {
            float s[NE];
#pragma unroll
            for (int e = 0; e < NE; ++e) s[e] = scores[t * NE + e];
            bool sel[NE];
#pragma unroll
            for (int e = 0; e < NE; ++e) sel[e] = false;
            for (int j = 0; j < k; ++j) {
                int best = 0; float bv = -3.4e38f;
#pragma unroll
                for (int e = 0; e < NE; ++e)
                    if (!sel[e] && s[e] > bv) { bv = s[e]; best = e; }
                sel[best] = true;
            }
#pragma unroll
            for (int e = 0; e < NE; ++e) selS[t][e] = sel[e] ? 1 : 0;
        }
        __syncthreads();
        if (t < NE) {
            int c = 0;
#pragma unroll
            for (int b = 0; b < NB; ++b) c += selS[b][t];
            counts[t] = (float)c;
        }
    }
}

// ====== 256x256 8-wave GEMM, BK=32, 3-buffer LDS, register operand double-buffer ======
// ds_reads of tile t+1 overlap MFMA of tile t; counted vmcnt(4), never drain-0 in steady state.
__global__ __launch_bounds__(512, 2) void gemm_kernel(const ushort_t* __restrict__ xb,
                                                      const ushort_t* __restrict__ wct,
                                                      const float* __restrict__ bias,
                                                      float* __restrict__ out) {
    __shared__ ushort_t ldsA[3][256 * 32];   // 3 x 16 KiB
    __shared__ ushort_t ldsB[3][256 * 32];   // 3 x 16 KiB

    int bid = blockIdx.x;
    int b = bid & 7;                 // batch -> XCD
    int tile = bid >> 3;             // 0..31
    int m0 = (tile >> 2) * 256;
    int n0 = (tile & 3) * 256;
    const ushort_t* A  = xb  + ((size_t)b * NS * ND) + (size_t)m0 * ND;
    const ushort_t* Bt = wct + ((size_t)b * ND * ND) + (size_t)n0 * ND;

    int t = threadIdx.x, lane = t & 63, wave = t >> 6;
    int wm = wave >> 2, wn = wave & 3;          // 2 x 4 wave grid, wave tile 128x64
    int fr = lane & 15, fq = lane >> 4;

    // ---- staging source (pre-swizzled slot: s' = s ^ ((row>>1)&3); LDS dest linear) ----
    int swz_s = (lane & 3) ^ ((lane >> 3) & 3);
    const ushort_t* srcA = A  + (size_t)(wave * 16 + (lane >> 2)) * ND + swz_s * 8;
    const ushort_t* srcB = Bt + (size_t)(wave * 16 + (lane >> 2)) * ND + swz_s * 8;
    int dst0 = wave * 512;            // ushort offset of gload dest (instr 0)
    int dst1 = (8 + wave) * 512;      // instr 1 (+128 rows)

    // ---- read-side fragment offsets (ushort units), swizzle s' = fq ^ ((fr>>1)&3) ----
    int swz_r = fq ^ ((fr >> 1) & 3);
    int offA = (wm * 128 + fr) * 32 + swz_r * 8;
    int offB = (wn * 64  + fr) * 32 + swz_r * 8;

    f32x4 acc[8][4];
#pragma unroll
    for (int i = 0; i < 8; ++i)
#pragma unroll
        for (int j = 0; j < 4; ++j) acc[i][j] = (f32x4){0.f, 0.f, 0.f, 0.f};

    const int NT = 32;   // K-tiles of BK=32

#define STAGE(kt, buf) do { \
    gload16(srcA + (kt) * 32,                     &ldsA[buf][dst0]); \
    gload16(srcA + (kt) * 32 + 128 * ND,          &ldsA[buf][dst1]); \
    gload16(srcB + (kt) * 32,                     &ldsB[buf][dst0]); \
    gload16(srcB + (kt) * 32 + 128 * ND,          &ldsB[buf][dst1]); \
} while (0)

#define READF(aR, bR, rb) do { \
    const ushort_t* pA_ = &ldsA[rb][0] + offA; \
    const ushort_t* pB_ = &ldsB[rb][0] + offB; \
    _Pragma("unroll") \
    for (int nj = 0; nj < 4; ++nj) bR[nj] = *(const bf16x8*)(pB_ + nj * 512); \
    _Pragma("unroll") \
    for (int mi = 0; mi < 8; ++mi) aR[mi] = *(const bf16x8*)(pA_ + mi * 512); \
} while (0)

#define MFMA_T(aR, bR) do { \
    __builtin_amdgcn_s_setprio(1); \
    _Pragma("unroll") \
    for (int mi = 0; mi < 8; ++mi) \
        _Pragma("unroll") \
        for (int nj = 0; nj < 4; ++nj) \
            acc[mi][nj] = __builtin_amdgcn_mfma_f32_16x16x32_bf16(aR[mi], bR[nj], acc[mi][nj], 0, 0, 0); \
    __builtin_amdgcn_s_setprio(0); \
} while (0)

#define TILE_END(j) do { \
    if ((j) + 2 < NT) { \
        asm volatile("s_waitcnt lgkmcnt(0)" ::: "memory"); \
        if ((j) + 3 < NT) asm volatile("s_waitcnt vmcnt(4)" ::: "memory"); \
        else              asm volatile("s_waitcnt vmcnt(0)" ::: "memory"); \
        __builtin_amdgcn_s_barrier(); \
    } \
} while (0)

    bf16x8 aX[8], bX[4], aY[8], bY[4];

    // ---- prologue: stage tiles 0,1,2 -> bufs 0,1,2; read tile 0 into X ----
    STAGE(0, 0); STAGE(1, 1); STAGE(2, 2);
    asm volatile("s_waitcnt vmcnt(4)" ::: "memory");   // T0,T1 landed
    __builtin_amdgcn_s_barrier();
    READF(aX, bX, 0);
    asm volatile("s_waitcnt lgkmcnt(0)" ::: "memory");
    __builtin_amdgcn_s_barrier();                      // buf0 reads done -> iter0 may overwrite buf0

    int cs = 0;   // kt % 3
    for (int kt = 0; kt < NT; kt += 2) {
        int rb = cs + 1; if (rb == 3) rb = 0;          // (kt+1) % 3
        // ---- even iter: MFMA tile kt (X); read kt+1 -> Y; stage kt+3 -> buf cs ----
        READF(aY, bY, rb);                             // kt+1 < NT always (kt <= 30)
        if (kt + 3 < NT) STAGE(kt + 3, cs);
        __builtin_amdgcn_sched_barrier(0);
        MFMA_T(aX, bX);
        __builtin_amdgcn_sched_barrier(0);
        TILE_END(kt);

        int rb2 = rb + 1; if (rb2 == 3) rb2 = 0;       // (kt+2) % 3
        // ---- odd iter: MFMA tile kt+1 (Y); read kt+2 -> X; stage kt+4 -> buf rb ----
        if (kt + 2 < NT) READF(aX, bX, rb2);
        if (kt + 4 < NT) STAGE(kt + 4, rb);
        __builtin_amdgcn_sched_barrier(0);
        MFMA_T(aY, bY);
        __builtin_amdgcn_sched_barrier(0);
        TILE_END(kt + 1);

        cs = rb2;
    }

#undef STAGE
#undef READF
#undef MFMA_T
#undef TILE_END

    // ---- epilogue: bias + fp32 store ----
    const float* bs = bias + b * ND;
    float* O = out + ((size_t)b * NS * ND);
#pragma unroll
    for (int mi = 0; mi < 8; ++mi) {
        int row = m0 + wm * 128 + mi * 16 + fq * 4;
#pragma unroll
        for (int nj = 0; nj < 4; ++nj) {
            int col = n0 + wn * 64 + nj * 16 + fr;
            float bv = bs[col];
            f32x4 v = acc[mi][nj];
#pragma unroll
            for (int r = 0; r < 4; ++r)
                O[(size_t)(row + r) * ND + col] = v[r] + bv;
        }
    }
}

extern "C" void kernel_launch(void* const* d_in, const int* in_sizes, int n_in,
                              void* d_out, int out_size, void* d_ws, size_t ws_size,
                              hipStream_t stream) {
    const float* x      = (const float*)d_in[0];
    const float* scores = (const float*)d_in[1];
    const float* Wx     = (const float*)d_in[2];
    const float* eb     = (const float*)d_in[3];
    const int*   kp     = (const int*)d_in[4];
    float* out = (float*)d_out;
    char* ws = (char*)d_ws;

    float*    bias  = (float*)(ws + 1024);
    ushort_t* xbuf  = (ushort_t*)(ws + 65536);
    ushort_t* wct   = (ushort_t*)(ws + 65536 + (size_t)NB * NS * ND * 2);
    float*    counts = out + (size_t)NB * NS * ND;

    prep_kernel<<<10273, 256, 0, stream>>>(x, scores, Wx, eb, kp, xbuf, wct, bias, counts);
    gemm_kernel<<<256, 512, 0, stream>>>(xbuf, wct, bias, out);
}